// Round 7
// baseline (907.846 us; speedup 1.0000x reference)
//
#include <hip/hip_runtime.h>
#include <hip/hip_bf16.h>

#define DIM 512
#define NCOLS 16384

typedef __bf16 bf16x8 __attribute__((ext_vector_type(8)));
typedef float f32x4 __attribute__((ext_vector_type(4)));

__device__ __forceinline__ unsigned short f2bf(float f) {
  unsigned u = __builtin_bit_cast(unsigned, f);
  u += 0x7FFFu + ((u >> 16) & 1u);
  return (unsigned short)(u >> 16);
}

// ---------------------------------------------------------------------------
// Stage 1: G = W^T W, f64 accumulate, LDS-tiled (unchanged from r5).
__global__ __launch_bounds__(256) void k_gram(const float* __restrict__ W,
                                              double* __restrict__ G) {
  __shared__ float Wa[16][34];
  __shared__ float Wb[16][34];
  const int t = threadIdx.x;
  const int tx = t & 15, ty = t >> 4;
  const int i0 = blockIdx.y * 32, j0 = blockIdx.x * 32;
  const int rr = t >> 4, c2 = (t & 15) * 2;
  double acc[2][2] = {{0, 0}, {0, 0}};

  for (int kr = 0; kr < DIM; kr += 16) {
    __syncthreads();
    *(float2*)&Wa[rr][c2] = *(const float2*)&W[(kr + rr) * DIM + i0 + c2];
    *(float2*)&Wb[rr][c2] = *(const float2*)&W[(kr + rr) * DIM + j0 + c2];
    __syncthreads();
#pragma unroll
    for (int r = 0; r < 16; ++r) {
      float2 wi = *(const float2*)&Wa[r][ty * 2];
      float2 wj = *(const float2*)&Wb[r][tx * 2];
      acc[0][0] += (double)wi.x * (double)wj.x;
      acc[0][1] += (double)wi.x * (double)wj.y;
      acc[1][0] += (double)wi.y * (double)wj.x;
      acc[1][1] += (double)wi.y * (double)wj.y;
    }
  }
#pragma unroll
  for (int a = 0; a < 2; ++a)
#pragma unroll
    for (int b = 0; b < 2; ++b)
      G[(i0 + ty * 2 + a) * DIM + j0 + tx * 2 + b] = acc[a][b];
}

// ---------------------------------------------------------------------------
// Stage 2a: 64x64 diag Cholesky, unscaled storage + lookahead (r6 design).
// 256 threads.  Thread t owns rows i=t>>2, j-stripe g=t&3 (unique element
// ownership -> race-free).  Per column the ONLY serial work is: 2 LDS reads,
// FMA chain, and ONE f64 div done by the (c+1,c+1) owner (lookahead).  All
// sqrt/scaling deferred to a single parallel pass at the end.
__global__ __launch_bounds__(256) void k_diag(double* __restrict__ G,
                                              float* __restrict__ Lf,
                                              int k) {
  __shared__ double A[64][65];
  __shared__ double invL[64];
  __shared__ double rsL[64];
  const int t = threadIdx.x;
  const int base = k * 64;
  const int i = t >> 2, g = t & 3;

  for (int e = t; e < 4096; e += 256)
    A[e >> 6][e & 63] = G[(base + (e >> 6)) * DIM + base + (e & 63)];
  __syncthreads();
  if (t == 0) invL[0] = 1.0 / A[0][0];
  __syncthreads();

#pragma unroll 1
  for (int c = 0; c < 64; ++c) {
    const double inv = invL[c];
    const double aic = A[i][c];
    const int j0 = (c + 1) + ((g - (c + 1)) & 3);
    for (int j = j0; j <= i; j += 4)
      A[i][j] -= aic * (A[j][c] * inv);
    if (c < 63 && t == (((c + 1) << 2) | ((c + 1) & 3)))
      invL[c + 1] = 1.0 / A[c + 1][c + 1];   // own element; lookahead div
    __syncthreads();
  }

  if (t < 64) rsL[t] = 1.0 / sqrt(A[t][t]);
  __syncthreads();
  for (int e = t; e < 4096; e += 256) {
    int r = e >> 6, j = e & 63;
    double val = (r >= j) ? A[r][j] * rsL[j] : 0.0;
    G[(base + r) * DIM + base + j] = val;       // scaled L for k_trsm staging
    Lf[(base + r) * DIM + base + j] = (float)val;
  }
}

// ---------------------------------------------------------------------------
// Stage 2b: panel TRSM, own kernel.  64-thread blocks (1 wave), grid = 7-k
// row-blocks, __launch_bounds__(64,1) so x[64] f64 (128 VGPR) stays in
// REGISTERS (the r4/r5 fusion at 512 threads forced a spill).
__global__ __launch_bounds__(64, 1) void k_trsm(double* __restrict__ G,
                                                float* __restrict__ Lf,
                                                int k) {
  __shared__ double Ls[64][65];
  __shared__ double invd[64];
  const int base = k * 64;
  const int tid = threadIdx.x;
  for (int e = tid; e < 4096; e += 64) {
    int i = e >> 6, j = e & 63;
    Ls[i][j] = G[(base + i) * DIM + base + j];
  }
  __syncthreads();
  invd[tid] = 1.0 / Ls[tid][tid];
  __syncthreads();

  const int r = base + 64 + blockIdx.x * 64 + tid;
  double x[64];
#pragma unroll
  for (int j = 0; j < 64; ++j) x[j] = G[r * DIM + base + j];
#pragma unroll
  for (int j = 0; j < 64; ++j) {
    double s0 = 0, s1 = 0, s2 = 0, s3 = 0;
#pragma unroll
    for (int c = 0; c < j; ++c) {
      double tt = x[c] * Ls[j][c];
      if ((c & 3) == 0) s0 += tt;
      else if ((c & 3) == 1) s1 += tt;
      else if ((c & 3) == 2) s2 += tt;
      else s3 += tt;
    }
    x[j] = (x[j] - ((s0 + s1) + (s2 + s3))) * invd[j];
  }
#pragma unroll
  for (int j = 0; j < 64; ++j) {
    G[r * DIM + base + j] = x[j];
    Lf[r * DIM + base + j] = (float)x[j];
  }
}

// ---------------------------------------------------------------------------
// Stage 2c: Schur update, LDS-tiled f64 (unchanged from r5).
__global__ __launch_bounds__(256) void k_syrk(double* __restrict__ G, int k) {
  __shared__ double Lat[64][34];
  __shared__ double Lbt[64][34];
  const int off = (k + 1) * 64, pb = k * 64;
  const int t = threadIdx.x;
  const int bx = blockIdx.x, by = blockIdx.y;
  if (bx > by) return;
  const int j0 = off + bx * 32, i0 = off + by * 32;
  const int tx = t & 15, ty = t >> 4;

  {
    const int ii = t >> 3, c0 = (t & 7) * 8;
    const double* gi = &G[(i0 + ii) * DIM + pb + c0];
    const double* gj = &G[(j0 + ii) * DIM + pb + c0];
#pragma unroll
    for (int q = 0; q < 4; ++q) {
      double2 va = *(const double2*)(gi + 2 * q);
      double2 vb = *(const double2*)(gj + 2 * q);
      Lat[c0 + 2 * q][ii] = va.x; Lat[c0 + 2 * q + 1][ii] = va.y;
      Lbt[c0 + 2 * q][ii] = vb.x; Lbt[c0 + 2 * q + 1][ii] = vb.y;
    }
  }
  __syncthreads();

  double acc[2][2] = {{0, 0}, {0, 0}};
#pragma unroll 8
  for (int c = 0; c < 64; ++c) {
    double2 la = *(const double2*)&Lat[c][ty * 2];
    double2 lb = *(const double2*)&Lbt[c][tx * 2];
    acc[0][0] += la.x * lb.x; acc[0][1] += la.x * lb.y;
    acc[1][0] += la.y * lb.x; acc[1][1] += la.y * lb.y;
  }
#pragma unroll
  for (int a = 0; a < 2; ++a)
#pragma unroll
    for (int b = 0; b < 2; ++b) {
      int ii = i0 + ty * 2 + a, jj = j0 + tx * 2 + b;
      G[ii * DIM + jj] -= acc[a][b];
    }
}

// ---------------------------------------------------------------------------
// Stage 3a: invert the 8 diagonal 64x64 blocks of L (unchanged).
__global__ __launch_bounds__(64) void k_dinv(const float* __restrict__ Lf,
                                             float* __restrict__ Minv) {
  __shared__ float Ld[64][65];
  const int lane = threadIdx.x;
  const int b = blockIdx.x * 64;
  for (int r = 0; r < 64; ++r) Ld[r][lane] = Lf[(b + r) * DIM + b + lane];
  __syncthreads();
  float y[64];
#pragma unroll
  for (int i = 0; i < 64; ++i) {
    float s = (i == lane) ? 1.f : 0.f;
#pragma unroll
    for (int c = 0; c < i; ++c) s -= Ld[i][c] * y[c];
    y[i] = s / Ld[i][i];
  }
  for (int i = 0; i < 64; ++i) Minv[(b + i) * DIM + b + lane] = y[i];
}

// ---------------------------------------------------------------------------
// Stage 3b: recursive combine (unchanged).
__global__ __launch_bounds__(256) void k_combT(const float* __restrict__ Lf,
                                               const float* __restrict__ Minv,
                                               float* __restrict__ T, int n) {
  const int p = blockIdx.z;
  const int rb = p * 2 * n + n, cb = p * 2 * n;
  const int j = blockIdx.x * 16 + (threadIdx.x & 15);
  const int i = blockIdx.y * 16 + (threadIdx.x >> 4);
  float acc = 0.f;
#pragma unroll 4
  for (int c = 0; c < n; ++c)
    acc += Lf[(rb + i) * DIM + cb + c] * Minv[(cb + c) * DIM + cb + j];
  T[p * n * n + i * n + j] = acc;
}

__global__ __launch_bounds__(256) void k_combO(float* __restrict__ Minv,
                                               const float* __restrict__ T, int n) {
  const int p = blockIdx.z;
  const int rb = p * 2 * n + n, cb = p * 2 * n;
  const int j = blockIdx.x * 16 + (threadIdx.x & 15);
  const int i = blockIdx.y * 16 + (threadIdx.x >> 4);
  float acc = 0.f;
#pragma unroll 4
  for (int c = 0; c < n; ++c)
    acc += Minv[(rb + i) * DIM + rb + c] * T[p * n * n + c * n + j];
  Minv[(rb + i) * DIM + cb + j] = -acc;
}

// ---------------------------------------------------------------------------
// Stage 4: U = W * Minv^T, LDS-tiled f32 (unchanged from r5).
__global__ __launch_bounds__(256) void k_formU(const float* __restrict__ W,
                                               const float* __restrict__ Minv,
                                               float* __restrict__ U) {
  __shared__ float Wt[32][34];
  __shared__ float Mt[32][34];
  const int t = threadIdx.x;
  const int tx = t & 15, ty = t >> 4;
  const int i0 = blockIdx.x * 32, r0 = blockIdx.y * 32;
  const int sr = t >> 3, sc = (t & 7) * 4;
  float acc[2][2] = {{0, 0}, {0, 0}};

  for (int kc = 0; kc < DIM; kc += 32) {
    __syncthreads();
    float4 vw = *(const float4*)&W[(r0 + sr) * DIM + kc + sc];
    float4 vm = *(const float4*)&Minv[(i0 + sr) * DIM + kc + sc];
    Wt[sc + 0][sr] = vw.x; Wt[sc + 1][sr] = vw.y;
    Wt[sc + 2][sr] = vw.z; Wt[sc + 3][sr] = vw.w;
    Mt[sc + 0][sr] = vm.x; Mt[sc + 1][sr] = vm.y;
    Mt[sc + 2][sr] = vm.z; Mt[sc + 3][sr] = vm.w;
    __syncthreads();
#pragma unroll 8
    for (int c = 0; c < 32; ++c) {
      float2 wv = *(const float2*)&Wt[c][ty * 2];
      float2 mv = *(const float2*)&Mt[c][tx * 2];
      acc[0][0] += wv.x * mv.x; acc[0][1] += wv.x * mv.y;
      acc[1][0] += wv.y * mv.x; acc[1][1] += wv.y * mv.y;
    }
  }
#pragma unroll
  for (int a = 0; a < 2; ++a)
#pragma unroll
    for (int b = 0; b < 2; ++b)
      U[(r0 + ty * 2 + a) * DIM + i0 + tx * 2 + b] = acc[a][b];
}

// ---------------------------------------------------------------------------
// Stage 5: P = U*diag(sigmoid(Dp))*U^T via bf16 MFMA (unchanged from r5).
__global__ __launch_bounds__(256) void k_formP(const float* __restrict__ Uin,
                                               const float* __restrict__ Dp,
                                               unsigned short* __restrict__ P) {
  __shared__ float dsh[DIM];
  __shared__ unsigned short As[64][40];
  __shared__ unsigned short Bs[64][40];
  const int t = threadIdx.x;
  const int lane = t & 63, w = t >> 6;
  const int i0 = blockIdx.y * 64, j0 = blockIdx.x * 64;
  const int row = t >> 2, seg = t & 3;

  dsh[t] = 1.f / (1.f + __expf(-Dp[t]));
  dsh[t + 256] = 1.f / (1.f + __expf(-Dp[t + 256]));

  f32x4 acc[4];
#pragma unroll
  for (int nf = 0; nf < 4; ++nf) acc[nf] = (f32x4){0.f, 0.f, 0.f, 0.f};

#pragma unroll 1
  for (int kc = 0; kc < DIM; kc += 32) {
    __syncthreads();
    const int c0 = kc + seg * 8;
    float4 ua = *(const float4*)&Uin[(i0 + row) * DIM + c0];
    float4 ub = *(const float4*)&Uin[(i0 + row) * DIM + c0 + 4];
    float4 va = *(const float4*)&Uin[(j0 + row) * DIM + c0];
    float4 vb = *(const float4*)&Uin[(j0 + row) * DIM + c0 + 4];
    uint4 pa, pb;
    pa.x = (unsigned)f2bf(ua.x * dsh[c0 + 0]) | ((unsigned)f2bf(ua.y * dsh[c0 + 1]) << 16);
    pa.y = (unsigned)f2bf(ua.z * dsh[c0 + 2]) | ((unsigned)f2bf(ua.w * dsh[c0 + 3]) << 16);
    pa.z = (unsigned)f2bf(ub.x * dsh[c0 + 4]) | ((unsigned)f2bf(ub.y * dsh[c0 + 5]) << 16);
    pa.w = (unsigned)f2bf(ub.z * dsh[c0 + 6]) | ((unsigned)f2bf(ub.w * dsh[c0 + 7]) << 16);
    pb.x = (unsigned)f2bf(va.x) | ((unsigned)f2bf(va.y) << 16);
    pb.y = (unsigned)f2bf(va.z) | ((unsigned)f2bf(va.w) << 16);
    pb.z = (unsigned)f2bf(vb.x) | ((unsigned)f2bf(vb.y) << 16);
    pb.w = (unsigned)f2bf(vb.z) | ((unsigned)f2bf(vb.w) << 16);
    *(uint4*)&As[row][seg * 8] = pa;
    *(uint4*)&Bs[row][seg * 8] = pb;
    __syncthreads();
    bf16x8 af = *(const bf16x8*)&As[w * 16 + (lane & 15)][(lane >> 4) * 8];
#pragma unroll
    for (int nf = 0; nf < 4; ++nf) {
      bf16x8 bf = *(const bf16x8*)&Bs[nf * 16 + (lane & 15)][(lane >> 4) * 8];
      acc[nf] = __builtin_amdgcn_mfma_f32_16x16x32_bf16(af, bf, acc[nf], 0, 0, 0);
    }
  }
#pragma unroll
  for (int nf = 0; nf < 4; ++nf)
#pragma unroll
    for (int r = 0; r < 4; ++r) {
      int ri = i0 + w * 16 + (lane >> 4) * 4 + r;
      int cj = j0 + nf * 16 + (lane & 15);
      P[ri * DIM + cj] = f2bf(acc[nf][r]);
    }
}

// ---------------------------------------------------------------------------
// Stage 6: out = P @ x via bf16 MFMA (unchanged).
__global__ __launch_bounds__(512) void k_gemm(const unsigned short* __restrict__ P,
                                              const float* __restrict__ X,
                                              float* __restrict__ out) {
  __shared__ unsigned short As[DIM][40];
  __shared__ unsigned short Bs[64][40];
  const int tid = threadIdx.x;
  const int lane = tid & 63;
  const int w = tid >> 6;
  const int bn = blockIdx.x * 64;
  const int kk = tid >> 4;
  const int nq = tid & 15;

  const unsigned short* prow = P + tid * DIM;
  uint4 a0 = *(const uint4*)(prow + 0);
  uint4 a1 = *(const uint4*)(prow + 8);
  uint4 a2 = *(const uint4*)(prow + 16);
  uint4 a3 = *(const uint4*)(prow + 24);
  float4 bx = *(const float4*)(X + kk * NCOLS + bn + nq * 4);

  f32x4 acc[4][4];
#pragma unroll
  for (int mf = 0; mf < 4; ++mf)
#pragma unroll
    for (int nf = 0; nf < 4; ++nf)
      acc[mf][nf] = (f32x4){0.f, 0.f, 0.f, 0.f};

#pragma unroll 1
  for (int t = 0; t < 16; ++t) {
    __syncthreads();
    *(uint4*)&As[tid][0] = a0;
    *(uint4*)&As[tid][8] = a1;
    *(uint4*)&As[tid][16] = a2;
    *(uint4*)&As[tid][24] = a3;
    Bs[nq * 4 + 0][kk] = f2bf(bx.x);
    Bs[nq * 4 + 1][kk] = f2bf(bx.y);
    Bs[nq * 4 + 2][kk] = f2bf(bx.z);
    Bs[nq * 4 + 3][kk] = f2bf(bx.w);
    if (t < 15) {
      const unsigned short* pn = prow + (t + 1) * 32;
      a0 = *(const uint4*)(pn + 0);
      a1 = *(const uint4*)(pn + 8);
      a2 = *(const uint4*)(pn + 16);
      a3 = *(const uint4*)(pn + 24);
      bx = *(const float4*)(X + ((t + 1) * 32 + kk) * NCOLS + bn + nq * 4);
    }
    __syncthreads();
    bf16x8 af[4], bf[4];
#pragma unroll
    for (int mf = 0; mf < 4; ++mf)
      af[mf] = *(const bf16x8*)&As[w * 64 + mf * 16 + (lane & 15)][(lane >> 4) * 8];
#pragma unroll
    for (int nf = 0; nf < 4; ++nf)
      bf[nf] = *(const bf16x8*)&Bs[nf * 16 + (lane & 15)][(lane >> 4) * 8];
#pragma unroll
    for (int mf = 0; mf < 4; ++mf)
#pragma unroll
      for (int nf = 0; nf < 4; ++nf)
        acc[mf][nf] = __builtin_amdgcn_mfma_f32_16x16x32_bf16(af[mf], bf[nf],
                                                              acc[mf][nf], 0, 0, 0);
  }

#pragma unroll
  for (int mf = 0; mf < 4; ++mf)
#pragma unroll
    for (int nf = 0; nf < 4; ++nf)
#pragma unroll
      for (int r = 0; r < 4; ++r) {
        int row = w * 64 + mf * 16 + (lane >> 4) * 4 + r;
        int col = bn + nf * 16 + (lane & 15);
        out[row * NCOLS + col] = acc[mf][nf][r];
      }
}

// ---------------------------------------------------------------------------
extern "C" void kernel_launch(void* const* d_in, const int* in_sizes, int n_in,
                              void* d_out, int out_size, void* d_ws, size_t ws_size,
                              hipStream_t stream) {
  const float* X = (const float*)d_in[0];
  const float* W = (const float*)d_in[1];
  const float* Dp = (const float*)d_in[2];
  float* out = (float*)d_out;

  char* ws = (char*)d_ws;
  double* G = (double*)ws;                          // 2 MB: Gram -> L (f64)
  float* Lf = (float*)(ws + (2u << 20));            // 1 MB: L (f32, row-major)
  float* Minv = (float*)(ws + (3u << 20));          // 1 MB: L^-1 (f32)
  float* U = (float*)(ws + (4u << 20));             // 1 MB
  unsigned short* P = (unsigned short*)(ws + (5u << 20));  // 0.5 MB bf16
  float* T = (float*)ws;  // comb temp ALIASES G (G dead before comb runs)

  k_gram<<<dim3(16, 16), 256, 0, stream>>>(W, G);
  hipMemsetAsync(Minv, 0, DIM * DIM * sizeof(float), stream);
  for (int k = 0; k < 8; ++k) {
    k_diag<<<1, 256, 0, stream>>>(G, Lf, k);
    int rem = 7 - k;
    if (rem > 0) {
      k_trsm<<<rem, 64, 0, stream>>>(G, Lf, k);
      k_syrk<<<dim3(rem * 2, rem * 2), 256, 0, stream>>>(G, k);
    }
  }
  k_dinv<<<8, 64, 0, stream>>>(Lf, Minv);
  for (int l = 0; l < 3; ++l) {
    int n = 64 << l, Pn = 4 >> l;
    k_combT<<<dim3(n / 16, n / 16, Pn), 256, 0, stream>>>(Lf, Minv, T, n);
    k_combO<<<dim3(n / 16, n / 16, Pn), 256, 0, stream>>>(Minv, T, n);
  }
  k_formU<<<dim3(16, 16), 256, 0, stream>>>(W, Minv, U);
  k_formP<<<dim3(8, 8), 256, 0, stream>>>(U, Dp, P);
  k_gemm<<<NCOLS / 64, 512, 0, stream>>>(P, X, out);
}

// Round 9
// 821.469 us; speedup vs baseline: 1.1051x; 1.1051x over previous
//
#include <hip/hip_runtime.h>
#include <hip/hip_bf16.h>

#define DIM 512
#define NCOLS 16384

typedef __bf16 bf16x8 __attribute__((ext_vector_type(8)));
typedef float f32x4 __attribute__((ext_vector_type(4)));

__device__ __forceinline__ unsigned short f2bf(float f) {
  unsigned u = __builtin_bit_cast(unsigned, f);
  u += 0x7FFFu + ((u >> 16) & 1u);
  return (unsigned short)(u >> 16);
}

// ---------------------------------------------------------------------------
// Stage 1: G = W^T W, f64 accumulate, LDS-tiled (unchanged from r5).
__global__ __launch_bounds__(256) void k_gram(const float* __restrict__ W,
                                              double* __restrict__ G) {
  __shared__ float Wa[16][34];
  __shared__ float Wb[16][34];
  const int t = threadIdx.x;
  const int tx = t & 15, ty = t >> 4;
  const int i0 = blockIdx.y * 32, j0 = blockIdx.x * 32;
  const int rr = t >> 4, c2 = (t & 15) * 2;
  double acc[2][2] = {{0, 0}, {0, 0}};

  for (int kr = 0; kr < DIM; kr += 16) {
    __syncthreads();
    *(float2*)&Wa[rr][c2] = *(const float2*)&W[(kr + rr) * DIM + i0 + c2];
    *(float2*)&Wb[rr][c2] = *(const float2*)&W[(kr + rr) * DIM + j0 + c2];
    __syncthreads();
#pragma unroll
    for (int r = 0; r < 16; ++r) {
      float2 wi = *(const float2*)&Wa[r][ty * 2];
      float2 wj = *(const float2*)&Wb[r][tx * 2];
      acc[0][0] += (double)wi.x * (double)wj.x;
      acc[0][1] += (double)wi.x * (double)wj.y;
      acc[1][0] += (double)wi.y * (double)wj.x;
      acc[1][1] += (double)wi.y * (double)wj.y;
    }
  }
#pragma unroll
  for (int a = 0; a < 2; ++a)
#pragma unroll
    for (int b = 0; b < 2; ++b)
      G[(i0 + ty * 2 + a) * DIM + j0 + tx * 2 + b] = acc[a][b];
}

// ---------------------------------------------------------------------------
// Stage 2a (r8): 64x64 diag Cholesky on ONE wave, registers only.
// r2's design with the fix it needed: __launch_bounds__(64,1) gives the
// 512-VGPR budget so a[64] f64 (128 VGPRs) does NOT spill (r2 died at the
// 256-VGPR default: 800KB scratch traffic).  r7's LDS version was
// latency-serialized (dependent LDS RMW chains + 64 barriers ->
// ~1730cy/column); here each column is: shfl broadcast -> rsqrt -> 63
// independent shfl+FMA, all in-register, no barriers, no LDS.
__global__ __launch_bounds__(64, 1) void k_diag(double* __restrict__ G,
                                                float* __restrict__ Lf,
                                                int k) {
  const int lane = threadIdx.x;
  const int base = k * 64;
  double a[64];
#pragma unroll
  for (int c = 0; c < 64; ++c)
    a[c] = G[(base + lane) * DIM + base + c];   // lane = row (upper garbage unused)

#pragma unroll
  for (int c = 0; c < 64; ++c) {
    double dcc = __shfl(a[c], c);     // true A[c][c] (lane c's lower value)
    double rs = 1.0 / sqrt(dcc);
    double Lic = a[c] * rs;           // final L[lane][c] (valid lane>=c)
    a[c] = Lic;
#pragma unroll
    for (int j = c + 1; j < 64; ++j) {
      double Ljc = __shfl(Lic, j);    // L[j][c] from lane j
      a[j] -= Lic * Ljc;              // garbage in upper region: never used
    }
  }

#pragma unroll
  for (int j = 0; j < 64; ++j) {
    double val = (lane >= j) ? a[j] : 0.0;
    G[(base + lane) * DIM + base + j] = val;    // scaled L for k_trsm staging
    Lf[(base + lane) * DIM + base + j] = (float)val;
  }
}

// ---------------------------------------------------------------------------
// Stage 2b: panel TRSM (unchanged from r7).  64-thread blocks (1 wave),
// __launch_bounds__(64,1) keeps x[64] f64 in registers.
__global__ __launch_bounds__(64, 1) void k_trsm(double* __restrict__ G,
                                                float* __restrict__ Lf,
                                                int k) {
  __shared__ double Ls[64][65];
  __shared__ double invd[64];
  const int base = k * 64;
  const int tid = threadIdx.x;
  for (int e = tid; e < 4096; e += 64) {
    int i = e >> 6, j = e & 63;
    Ls[i][j] = G[(base + i) * DIM + base + j];
  }
  __syncthreads();
  invd[tid] = 1.0 / Ls[tid][tid];
  __syncthreads();

  const int r = base + 64 + blockIdx.x * 64 + tid;
  double x[64];
#pragma unroll
  for (int j = 0; j < 64; ++j) x[j] = G[r * DIM + base + j];
#pragma unroll
  for (int j = 0; j < 64; ++j) {
    double s0 = 0, s1 = 0, s2 = 0, s3 = 0;
#pragma unroll
    for (int c = 0; c < j; ++c) {
      double tt = x[c] * Ls[j][c];
      if ((c & 3) == 0) s0 += tt;
      else if ((c & 3) == 1) s1 += tt;
      else if ((c & 3) == 2) s2 += tt;
      else s3 += tt;
    }
    x[j] = (x[j] - ((s0 + s1) + (s2 + s3))) * invd[j];
  }
#pragma unroll
  for (int j = 0; j < 64; ++j) {
    G[r * DIM + base + j] = x[j];
    Lf[r * DIM + base + j] = (float)x[j];
  }
}

// ---------------------------------------------------------------------------
// Stage 2c: Schur update, LDS-tiled f64 (unchanged from r5).
__global__ __launch_bounds__(256) void k_syrk(double* __restrict__ G, int k) {
  __shared__ double Lat[64][34];
  __shared__ double Lbt[64][34];
  const int off = (k + 1) * 64, pb = k * 64;
  const int t = threadIdx.x;
  const int bx = blockIdx.x, by = blockIdx.y;
  if (bx > by) return;
  const int j0 = off + bx * 32, i0 = off + by * 32;
  const int tx = t & 15, ty = t >> 4;

  {
    const int ii = t >> 3, c0 = (t & 7) * 8;
    const double* gi = &G[(i0 + ii) * DIM + pb + c0];
    const double* gj = &G[(j0 + ii) * DIM + pb + c0];
#pragma unroll
    for (int q = 0; q < 4; ++q) {
      double2 va = *(const double2*)(gi + 2 * q);
      double2 vb = *(const double2*)(gj + 2 * q);
      Lat[c0 + 2 * q][ii] = va.x; Lat[c0 + 2 * q + 1][ii] = va.y;
      Lbt[c0 + 2 * q][ii] = vb.x; Lbt[c0 + 2 * q + 1][ii] = vb.y;
    }
  }
  __syncthreads();

  double acc[2][2] = {{0, 0}, {0, 0}};
#pragma unroll 8
  for (int c = 0; c < 64; ++c) {
    double2 la = *(const double2*)&Lat[c][ty * 2];
    double2 lb = *(const double2*)&Lbt[c][tx * 2];
    acc[0][0] += la.x * lb.x; acc[0][1] += la.x * lb.y;
    acc[1][0] += la.y * lb.x; acc[1][1] += la.y * lb.y;
  }
#pragma unroll
  for (int a = 0; a < 2; ++a)
#pragma unroll
    for (int b = 0; b < 2; ++b) {
      int ii = i0 + ty * 2 + a, jj = j0 + tx * 2 + b;
      G[ii * DIM + jj] -= acc[a][b];
    }
}

// ---------------------------------------------------------------------------
// Stage 3a: invert the 8 diagonal 64x64 blocks of L (unchanged).
__global__ __launch_bounds__(64) void k_dinv(const float* __restrict__ Lf,
                                             float* __restrict__ Minv) {
  __shared__ float Ld[64][65];
  const int lane = threadIdx.x;
  const int b = blockIdx.x * 64;
  for (int r = 0; r < 64; ++r) Ld[r][lane] = Lf[(b + r) * DIM + b + lane];
  __syncthreads();
  float y[64];
#pragma unroll
  for (int i = 0; i < 64; ++i) {
    float s = (i == lane) ? 1.f : 0.f;
#pragma unroll
    for (int c = 0; c < i; ++c) s -= Ld[i][c] * y[c];
    y[i] = s / Ld[i][i];
  }
  for (int i = 0; i < 64; ++i) Minv[(b + i) * DIM + b + lane] = y[i];
}

// ---------------------------------------------------------------------------
// Stage 3b: recursive combine (unchanged).
__global__ __launch_bounds__(256) void k_combT(const float* __restrict__ Lf,
                                               const float* __restrict__ Minv,
                                               float* __restrict__ T, int n) {
  const int p = blockIdx.z;
  const int rb = p * 2 * n + n, cb = p * 2 * n;
  const int j = blockIdx.x * 16 + (threadIdx.x & 15);
  const int i = blockIdx.y * 16 + (threadIdx.x >> 4);
  float acc = 0.f;
#pragma unroll 4
  for (int c = 0; c < n; ++c)
    acc += Lf[(rb + i) * DIM + cb + c] * Minv[(cb + c) * DIM + cb + j];
  T[p * n * n + i * n + j] = acc;
}

__global__ __launch_bounds__(256) void k_combO(float* __restrict__ Minv,
                                               const float* __restrict__ T, int n) {
  const int p = blockIdx.z;
  const int rb = p * 2 * n + n, cb = p * 2 * n;
  const int j = blockIdx.x * 16 + (threadIdx.x & 15);
  const int i = blockIdx.y * 16 + (threadIdx.x >> 4);
  float acc = 0.f;
#pragma unroll 4
  for (int c = 0; c < n; ++c)
    acc += Minv[(rb + i) * DIM + rb + c] * T[p * n * n + c * n + j];
  Minv[(rb + i) * DIM + cb + j] = -acc;
}

// ---------------------------------------------------------------------------
// Stage 4: U = W * Minv^T, LDS-tiled f32 (unchanged from r5).
__global__ __launch_bounds__(256) void k_formU(const float* __restrict__ W,
                                               const float* __restrict__ Minv,
                                               float* __restrict__ U) {
  __shared__ float Wt[32][34];
  __shared__ float Mt[32][34];
  const int t = threadIdx.x;
  const int tx = t & 15, ty = t >> 4;
  const int i0 = blockIdx.x * 32, r0 = blockIdx.y * 32;
  const int sr = t >> 3, sc = (t & 7) * 4;
  float acc[2][2] = {{0, 0}, {0, 0}};

  for (int kc = 0; kc < DIM; kc += 32) {
    __syncthreads();
    float4 vw = *(const float4*)&W[(r0 + sr) * DIM + kc + sc];
    float4 vm = *(const float4*)&Minv[(i0 + sr) * DIM + kc + sc];
    Wt[sc + 0][sr] = vw.x; Wt[sc + 1][sr] = vw.y;
    Wt[sc + 2][sr] = vw.z; Wt[sc + 3][sr] = vw.w;
    Mt[sc + 0][sr] = vm.x; Mt[sc + 1][sr] = vm.y;
    Mt[sc + 2][sr] = vm.z; Mt[sc + 3][sr] = vm.w;
    __syncthreads();
#pragma unroll 8
    for (int c = 0; c < 32; ++c) {
      float2 wv = *(const float2*)&Wt[c][ty * 2];
      float2 mv = *(const float2*)&Mt[c][tx * 2];
      acc[0][0] += wv.x * mv.x; acc[0][1] += wv.x * mv.y;
      acc[1][0] += wv.y * mv.x; acc[1][1] += wv.y * mv.y;
    }
  }
#pragma unroll
  for (int a = 0; a < 2; ++a)
#pragma unroll
    for (int b = 0; b < 2; ++b)
      U[(r0 + ty * 2 + a) * DIM + i0 + tx * 2 + b] = acc[a][b];
}

// ---------------------------------------------------------------------------
// Stage 5: P = U*diag(sigmoid(Dp))*U^T via bf16 MFMA (unchanged from r5).
__global__ __launch_bounds__(256) void k_formP(const float* __restrict__ Uin,
                                               const float* __restrict__ Dp,
                                               unsigned short* __restrict__ P) {
  __shared__ float dsh[DIM];
  __shared__ unsigned short As[64][40];
  __shared__ unsigned short Bs[64][40];
  const int t = threadIdx.x;
  const int lane = t & 63, w = t >> 6;
  const int i0 = blockIdx.y * 64, j0 = blockIdx.x * 64;
  const int row = t >> 2, seg = t & 3;

  dsh[t] = 1.f / (1.f + __expf(-Dp[t]));
  dsh[t + 256] = 1.f / (1.f + __expf(-Dp[t + 256]));

  f32x4 acc[4];
#pragma unroll
  for (int nf = 0; nf < 4; ++nf) acc[nf] = (f32x4){0.f, 0.f, 0.f, 0.f};

#pragma unroll 1
  for (int kc = 0; kc < DIM; kc += 32) {
    __syncthreads();
    const int c0 = kc + seg * 8;
    float4 ua = *(const float4*)&Uin[(i0 + row) * DIM + c0];
    float4 ub = *(const float4*)&Uin[(i0 + row) * DIM + c0 + 4];
    float4 va = *(const float4*)&Uin[(j0 + row) * DIM + c0];
    float4 vb = *(const float4*)&Uin[(j0 + row) * DIM + c0 + 4];
    uint4 pa, pb;
    pa.x = (unsigned)f2bf(ua.x * dsh[c0 + 0]) | ((unsigned)f2bf(ua.y * dsh[c0 + 1]) << 16);
    pa.y = (unsigned)f2bf(ua.z * dsh[c0 + 2]) | ((unsigned)f2bf(ua.w * dsh[c0 + 3]) << 16);
    pa.z = (unsigned)f2bf(ub.x * dsh[c0 + 4]) | ((unsigned)f2bf(ub.y * dsh[c0 + 5]) << 16);
    pa.w = (unsigned)f2bf(ub.z * dsh[c0 + 6]) | ((unsigned)f2bf(ub.w * dsh[c0 + 7]) << 16);
    pb.x = (unsigned)f2bf(va.x) | ((unsigned)f2bf(va.y) << 16);
    pb.y = (unsigned)f2bf(va.z) | ((unsigned)f2bf(va.w) << 16);
    pb.z = (unsigned)f2bf(vb.x) | ((unsigned)f2bf(vb.y) << 16);
    pb.w = (unsigned)f2bf(vb.z) | ((unsigned)f2bf(vb.w) << 16);
    *(uint4*)&As[row][seg * 8] = pa;
    *(uint4*)&Bs[row][seg * 8] = pb;
    __syncthreads();
    bf16x8 af = *(const bf16x8*)&As[w * 16 + (lane & 15)][(lane >> 4) * 8];
#pragma unroll
    for (int nf = 0; nf < 4; ++nf) {
      bf16x8 bf = *(const bf16x8*)&Bs[nf * 16 + (lane & 15)][(lane >> 4) * 8];
      acc[nf] = __builtin_amdgcn_mfma_f32_16x16x32_bf16(af, bf, acc[nf], 0, 0, 0);
    }
  }
#pragma unroll
  for (int nf = 0; nf < 4; ++nf)
#pragma unroll
    for (int r = 0; r < 4; ++r) {
      int ri = i0 + w * 16 + (lane >> 4) * 4 + r;
      int cj = j0 + nf * 16 + (lane & 15);
      P[ri * DIM + cj] = f2bf(acc[nf][r]);
    }
}

// ---------------------------------------------------------------------------
// Stage 6: out = P @ x via bf16 MFMA (unchanged).
__global__ __launch_bounds__(512) void k_gemm(const unsigned short* __restrict__ P,
                                              const float* __restrict__ X,
                                              float* __restrict__ out) {
  __shared__ unsigned short As[DIM][40];
  __shared__ unsigned short Bs[64][40];
  const int tid = threadIdx.x;
  const int lane = tid & 63;
  const int w = tid >> 6;
  const int bn = blockIdx.x * 64;
  const int kk = tid >> 4;
  const int nq = tid & 15;

  const unsigned short* prow = P + tid * DIM;
  uint4 a0 = *(const uint4*)(prow + 0);
  uint4 a1 = *(const uint4*)(prow + 8);
  uint4 a2 = *(const uint4*)(prow + 16);
  uint4 a3 = *(const uint4*)(prow + 24);
  float4 bx = *(const float4*)(X + kk * NCOLS + bn + nq * 4);

  f32x4 acc[4][4];
#pragma unroll
  for (int mf = 0; mf < 4; ++mf)
#pragma unroll
    for (int nf = 0; nf < 4; ++nf)
      acc[mf][nf] = (f32x4){0.f, 0.f, 0.f, 0.f};

#pragma unroll 1
  for (int t = 0; t < 16; ++t) {
    __syncthreads();
    *(uint4*)&As[tid][0] = a0;
    *(uint4*)&As[tid][8] = a1;
    *(uint4*)&As[tid][16] = a2;
    *(uint4*)&As[tid][24] = a3;
    Bs[nq * 4 + 0][kk] = f2bf(bx.x);
    Bs[nq * 4 + 1][kk] = f2bf(bx.y);
    Bs[nq * 4 + 2][kk] = f2bf(bx.z);
    Bs[nq * 4 + 3][kk] = f2bf(bx.w);
    if (t < 15) {
      const unsigned short* pn = prow + (t + 1) * 32;
      a0 = *(const uint4*)(pn + 0);
      a1 = *(const uint4*)(pn + 8);
      a2 = *(const uint4*)(pn + 16);
      a3 = *(const uint4*)(pn + 24);
      bx = *(const float4*)(X + ((t + 1) * 32 + kk) * NCOLS + bn + nq * 4);
    }
    __syncthreads();
    bf16x8 af[4], bf[4];
#pragma unroll
    for (int mf = 0; mf < 4; ++mf)
      af[mf] = *(const bf16x8*)&As[w * 64 + mf * 16 + (lane & 15)][(lane >> 4) * 8];
#pragma unroll
    for (int nf = 0; nf < 4; ++nf)
      bf[nf] = *(const bf16x8*)&Bs[nf * 16 + (lane & 15)][(lane >> 4) * 8];
#pragma unroll
    for (int mf = 0; mf < 4; ++mf)
#pragma unroll
      for (int nf = 0; nf < 4; ++nf)
        acc[mf][nf] = __builtin_amdgcn_mfma_f32_16x16x32_bf16(af[mf], bf[nf],
                                                              acc[mf][nf], 0, 0, 0);
  }

#pragma unroll
  for (int mf = 0; mf < 4; ++mf)
#pragma unroll
    for (int nf = 0; nf < 4; ++nf)
#pragma unroll
      for (int r = 0; r < 4; ++r) {
        int row = w * 64 + mf * 16 + (lane >> 4) * 4 + r;
        int col = bn + nf * 16 + (lane & 15);
        out[row * NCOLS + col] = acc[mf][nf][r];
      }
}

// ---------------------------------------------------------------------------
extern "C" void kernel_launch(void* const* d_in, const int* in_sizes, int n_in,
                              void* d_out, int out_size, void* d_ws, size_t ws_size,
                              hipStream_t stream) {
  const float* X = (const float*)d_in[0];
  const float* W = (const float*)d_in[1];
  const float* Dp = (const float*)d_in[2];
  float* out = (float*)d_out;

  char* ws = (char*)d_ws;
  double* G = (double*)ws;                          // 2 MB: Gram -> L (f64)
  float* Lf = (float*)(ws + (2u << 20));            // 1 MB: L (f32, row-major)
  float* Minv = (float*)(ws + (3u << 20));          // 1 MB: L^-1 (f32)
  float* U = (float*)(ws + (4u << 20));             // 1 MB
  unsigned short* P = (unsigned short*)(ws + (5u << 20));  // 0.5 MB bf16
  float* T = (float*)ws;  // comb temp ALIASES G (G dead before comb runs)

  k_gram<<<dim3(16, 16), 256, 0, stream>>>(W, G);
  hipMemsetAsync(Minv, 0, DIM * DIM * sizeof(float), stream);
  for (int k = 0; k < 8; ++k) {
    k_diag<<<1, 64, 0, stream>>>(G, Lf, k);
    int rem = 7 - k;
    if (rem > 0) {
      k_trsm<<<rem, 64, 0, stream>>>(G, Lf, k);
      k_syrk<<<dim3(rem * 2, rem * 2), 256, 0, stream>>>(G, k);
    }
  }
  k_dinv<<<8, 64, 0, stream>>>(Lf, Minv);
  for (int l = 0; l < 3; ++l) {
    int n = 64 << l, Pn = 4 >> l;
    k_combT<<<dim3(n / 16, n / 16, Pn), 256, 0, stream>>>(Lf, Minv, T, n);
    k_combO<<<dim3(n / 16, n / 16, Pn), 256, 0, stream>>>(Minv, T, n);
  }
  k_formU<<<dim3(16, 16), 256, 0, stream>>>(W, Minv, U);
  k_formP<<<dim3(8, 8), 256, 0, stream>>>(U, Dp, P);
  k_gemm<<<NCOLS / 64, 512, 0, stream>>>(P, X, out);
}

// Round 10
// 649.563 us; speedup vs baseline: 1.3976x; 1.2646x over previous
//
#include <hip/hip_runtime.h>
#include <hip/hip_bf16.h>

#define DIM 512
#define NCOLS 16384
#define PB 32  // panel width for the factorization chain (r10: 64 -> 32,
               // because the unrolled diag kernel's CODE is O(PB^2): at 64 it
               // was ~80KB (> 32KB L1I) and k_diag was ifetch-bound at 42us)

typedef __bf16 bf16x8 __attribute__((ext_vector_type(8)));
typedef float f32x4 __attribute__((ext_vector_type(4)));

__device__ __forceinline__ unsigned short f2bf(float f) {
  unsigned u = __builtin_bit_cast(unsigned, f);
  u += 0x7FFFu + ((u >> 16) & 1u);
  return (unsigned short)(u >> 16);
}

// ---------------------------------------------------------------------------
// Stage 1: G = W^T W, f64 accumulate, LDS-tiled (unchanged from r5).
__global__ __launch_bounds__(256) void k_gram(const float* __restrict__ W,
                                              double* __restrict__ G) {
  __shared__ float Wa[16][34];
  __shared__ float Wb[16][34];
  const int t = threadIdx.x;
  const int tx = t & 15, ty = t >> 4;
  const int i0 = blockIdx.y * 32, j0 = blockIdx.x * 32;
  const int rr = t >> 4, c2 = (t & 15) * 2;
  double acc[2][2] = {{0, 0}, {0, 0}};

  for (int kr = 0; kr < DIM; kr += 16) {
    __syncthreads();
    *(float2*)&Wa[rr][c2] = *(const float2*)&W[(kr + rr) * DIM + i0 + c2];
    *(float2*)&Wb[rr][c2] = *(const float2*)&W[(kr + rr) * DIM + j0 + c2];
    __syncthreads();
#pragma unroll
    for (int r = 0; r < 16; ++r) {
      float2 wi = *(const float2*)&Wa[r][ty * 2];
      float2 wj = *(const float2*)&Wb[r][tx * 2];
      acc[0][0] += (double)wi.x * (double)wj.x;
      acc[0][1] += (double)wi.x * (double)wj.y;
      acc[1][0] += (double)wi.y * (double)wj.x;
      acc[1][1] += (double)wi.y * (double)wj.y;
    }
  }
#pragma unroll
  for (int a = 0; a < 2; ++a)
#pragma unroll
    for (int b = 0; b < 2; ++b)
      G[(i0 + ty * 2 + a) * DIM + j0 + tx * 2 + b] = acc[a][b];
}

// ---------------------------------------------------------------------------
// Stage 2a (r10): 32x32 diag Cholesky on ONE wave, registers only.
// Same structure as r8 but PB=32: unrolled body ~15KB of code (fits L1I;
// the PB=64 version was ~80KB and ifetch-bound: FETCH 86KB = 32 data + 54
// code per dispatch).  a[32] = 64 VGPR, no spill risk.  Lanes 32-63 mirror
// rows 0-31 (harmless duplicates; writes guarded).
__global__ __launch_bounds__(64, 1) void k_diag(double* __restrict__ G,
                                                float* __restrict__ Lf,
                                                int k) {
  const int lane = threadIdx.x;
  const int base = k * PB;
  const int row = lane & 31;            // lanes 32-63 duplicate rows 0-31
  double a[32];
#pragma unroll
  for (int c = 0; c < 32; ++c)
    a[c] = G[(base + row) * DIM + base + c];

#pragma unroll
  for (int c = 0; c < 32; ++c) {
    double dcc = __shfl(a[c], c);       // A[c][c] from lane c
    double rs = 1.0 / sqrt(dcc);
    double Lic = a[c] * rs;             // final L[row][c]
    a[c] = Lic;
#pragma unroll
    for (int j = c + 1; j < 32; ++j) {
      double Ljc = __shfl(Lic, j);      // L[j][c] from lane j
      a[j] -= Lic * Ljc;
    }
  }

  if (lane < 32) {
#pragma unroll
    for (int j = 0; j < 32; ++j) {
      double val = (row >= j) ? a[j] : 0.0;
      G[(base + row) * DIM + base + j] = val;
      Lf[(base + row) * DIM + base + j] = (float)val;
    }
  }
}

// ---------------------------------------------------------------------------
// Stage 2b (r10): panel TRSM, PB=32.  64-thread blocks, x[32] = 64 VGPR
// stays comfortably in registers; Ls 32x33 f64 = 8.4KB LDS.
__global__ __launch_bounds__(64, 1) void k_trsm(double* __restrict__ G,
                                                float* __restrict__ Lf,
                                                int k) {
  __shared__ double Ls[32][33];
  __shared__ double invd[32];
  const int base = k * PB;
  const int tid = threadIdx.x;
  for (int e = tid; e < 1024; e += 64) {
    int i = e >> 5, j = e & 31;
    Ls[i][j] = G[(base + i) * DIM + base + j];
  }
  __syncthreads();
  if (tid < 32) invd[tid] = 1.0 / Ls[tid][tid];
  __syncthreads();

  const int r = base + PB + blockIdx.x * 64 + tid;
  if (r >= DIM) return;
  double x[32];
#pragma unroll
  for (int j = 0; j < 32; ++j) x[j] = G[r * DIM + base + j];
#pragma unroll
  for (int j = 0; j < 32; ++j) {
    double s0 = 0, s1 = 0, s2 = 0, s3 = 0;
#pragma unroll
    for (int c = 0; c < j; ++c) {
      double tt = x[c] * Ls[j][c];
      if ((c & 3) == 0) s0 += tt;
      else if ((c & 3) == 1) s1 += tt;
      else if ((c & 3) == 2) s2 += tt;
      else s3 += tt;
    }
    x[j] = (x[j] - ((s0 + s1) + (s2 + s3))) * invd[j];
  }
#pragma unroll
  for (int j = 0; j < 32; ++j) {
    G[r * DIM + base + j] = x[j];
    Lf[r * DIM + base + j] = (float)x[j];
  }
}

// ---------------------------------------------------------------------------
// Stage 2c (r10): Schur update, rank-32, LDS-tiled f64.  32x32 output tile,
// 2x2 micro; LDS transposed [c][local] with pad.
__global__ __launch_bounds__(256) void k_syrk(double* __restrict__ G, int k) {
  __shared__ double Lat[32][34];
  __shared__ double Lbt[32][34];
  const int off = (k + 1) * PB, pb = k * PB;
  const int t = threadIdx.x;
  const int bx = blockIdx.x, by = blockIdx.y;
  if (bx > by) return;
  const int j0 = off + bx * 32, i0 = off + by * 32;
  const int tx = t & 15, ty = t >> 4;

  {  // stage: 32 rows x 32 c's; thread: row t>>3, 4 c's at (t&7)*4
    const int ii = t >> 3, c0 = (t & 7) * 4;
    const double* gi = &G[(i0 + ii) * DIM + pb + c0];
    const double* gj = &G[(j0 + ii) * DIM + pb + c0];
#pragma unroll
    for (int q = 0; q < 2; ++q) {
      double2 va = *(const double2*)(gi + 2 * q);
      double2 vb = *(const double2*)(gj + 2 * q);
      Lat[c0 + 2 * q][ii] = va.x; Lat[c0 + 2 * q + 1][ii] = va.y;
      Lbt[c0 + 2 * q][ii] = vb.x; Lbt[c0 + 2 * q + 1][ii] = vb.y;
    }
  }
  __syncthreads();

  double acc[2][2] = {{0, 0}, {0, 0}};
#pragma unroll 8
  for (int c = 0; c < 32; ++c) {
    double2 la = *(const double2*)&Lat[c][ty * 2];
    double2 lb = *(const double2*)&Lbt[c][tx * 2];
    acc[0][0] += la.x * lb.x; acc[0][1] += la.x * lb.y;
    acc[1][0] += la.y * lb.x; acc[1][1] += la.y * lb.y;
  }
#pragma unroll
  for (int a = 0; a < 2; ++a)
#pragma unroll
    for (int b = 0; b < 2; ++b) {
      int ii = i0 + ty * 2 + a, jj = j0 + tx * 2 + b;
      G[ii * DIM + jj] -= acc[a][b];
    }
}

// ---------------------------------------------------------------------------
// Stage 3a: invert the 8 diagonal 64x64 blocks of L (unchanged; only reads
// the lower triangle of each 64-block, which the 32-panel chain fully writes).
__global__ __launch_bounds__(64) void k_dinv(const float* __restrict__ Lf,
                                             float* __restrict__ Minv) {
  __shared__ float Ld[64][65];
  const int lane = threadIdx.x;
  const int b = blockIdx.x * 64;
  for (int r = 0; r < 64; ++r) Ld[r][lane] = Lf[(b + r) * DIM + b + lane];
  __syncthreads();
  float y[64];
#pragma unroll
  for (int i = 0; i < 64; ++i) {
    float s = (i == lane) ? 1.f : 0.f;
#pragma unroll
    for (int c = 0; c < i; ++c) s -= Ld[i][c] * y[c];
    y[i] = s / Ld[i][i];
  }
  for (int i = 0; i < 64; ++i) Minv[(b + i) * DIM + b + lane] = y[i];
}

// ---------------------------------------------------------------------------
// Stage 3b: recursive combine (unchanged).
__global__ __launch_bounds__(256) void k_combT(const float* __restrict__ Lf,
                                               const float* __restrict__ Minv,
                                               float* __restrict__ T, int n) {
  const int p = blockIdx.z;
  const int rb = p * 2 * n + n, cb = p * 2 * n;
  const int j = blockIdx.x * 16 + (threadIdx.x & 15);
  const int i = blockIdx.y * 16 + (threadIdx.x >> 4);
  float acc = 0.f;
#pragma unroll 4
  for (int c = 0; c < n; ++c)
    acc += Lf[(rb + i) * DIM + cb + c] * Minv[(cb + c) * DIM + cb + j];
  T[p * n * n + i * n + j] = acc;
}

__global__ __launch_bounds__(256) void k_combO(float* __restrict__ Minv,
                                               const float* __restrict__ T, int n) {
  const int p = blockIdx.z;
  const int rb = p * 2 * n + n, cb = p * 2 * n;
  const int j = blockIdx.x * 16 + (threadIdx.x & 15);
  const int i = blockIdx.y * 16 + (threadIdx.x >> 4);
  float acc = 0.f;
#pragma unroll 4
  for (int c = 0; c < n; ++c)
    acc += Minv[(rb + i) * DIM + rb + c] * T[p * n * n + c * n + j];
  Minv[(rb + i) * DIM + cb + j] = -acc;
}

// ---------------------------------------------------------------------------
// Stage 4: U = W * Minv^T, LDS-tiled f32 (unchanged from r5).
__global__ __launch_bounds__(256) void k_formU(const float* __restrict__ W,
                                               const float* __restrict__ Minv,
                                               float* __restrict__ U) {
  __shared__ float Wt[32][34];
  __shared__ float Mt[32][34];
  const int t = threadIdx.x;
  const int tx = t & 15, ty = t >> 4;
  const int i0 = blockIdx.x * 32, r0 = blockIdx.y * 32;
  const int sr = t >> 3, sc = (t & 7) * 4;
  float acc[2][2] = {{0, 0}, {0, 0}};

  for (int kc = 0; kc < DIM; kc += 32) {
    __syncthreads();
    float4 vw = *(const float4*)&W[(r0 + sr) * DIM + kc + sc];
    float4 vm = *(const float4*)&Minv[(i0 + sr) * DIM + kc + sc];
    Wt[sc + 0][sr] = vw.x; Wt[sc + 1][sr] = vw.y;
    Wt[sc + 2][sr] = vw.z; Wt[sc + 3][sr] = vw.w;
    Mt[sc + 0][sr] = vm.x; Mt[sc + 1][sr] = vm.y;
    Mt[sc + 2][sr] = vm.z; Mt[sc + 3][sr] = vm.w;
    __syncthreads();
#pragma unroll 8
    for (int c = 0; c < 32; ++c) {
      float2 wv = *(const float2*)&Wt[c][ty * 2];
      float2 mv = *(const float2*)&Mt[c][tx * 2];
      acc[0][0] += wv.x * mv.x; acc[0][1] += wv.x * mv.y;
      acc[1][0] += wv.y * mv.x; acc[1][1] += wv.y * mv.y;
    }
  }
#pragma unroll
  for (int a = 0; a < 2; ++a)
#pragma unroll
    for (int b = 0; b < 2; ++b)
      U[(r0 + ty * 2 + a) * DIM + i0 + tx * 2 + b] = acc[a][b];
}

// ---------------------------------------------------------------------------
// Stage 5: P = U*diag(sigmoid(Dp))*U^T via bf16 MFMA (unchanged from r5).
__global__ __launch_bounds__(256) void k_formP(const float* __restrict__ Uin,
                                               const float* __restrict__ Dp,
                                               unsigned short* __restrict__ P) {
  __shared__ float dsh[DIM];
  __shared__ unsigned short As[64][40];
  __shared__ unsigned short Bs[64][40];
  const int t = threadIdx.x;
  const int lane = t & 63, w = t >> 6;
  const int i0 = blockIdx.y * 64, j0 = blockIdx.x * 64;
  const int row = t >> 2, seg = t & 3;

  dsh[t] = 1.f / (1.f + __expf(-Dp[t]));
  dsh[t + 256] = 1.f / (1.f + __expf(-Dp[t + 256]));

  f32x4 acc[4];
#pragma unroll
  for (int nf = 0; nf < 4; ++nf) acc[nf] = (f32x4){0.f, 0.f, 0.f, 0.f};

#pragma unroll 1
  for (int kc = 0; kc < DIM; kc += 32) {
    __syncthreads();
    const int c0 = kc + seg * 8;
    float4 ua = *(const float4*)&Uin[(i0 + row) * DIM + c0];
    float4 ub = *(const float4*)&Uin[(i0 + row) * DIM + c0 + 4];
    float4 va = *(const float4*)&Uin[(j0 + row) * DIM + c0];
    float4 vb = *(const float4*)&Uin[(j0 + row) * DIM + c0 + 4];
    uint4 pa, pb;
    pa.x = (unsigned)f2bf(ua.x * dsh[c0 + 0]) | ((unsigned)f2bf(ua.y * dsh[c0 + 1]) << 16);
    pa.y = (unsigned)f2bf(ua.z * dsh[c0 + 2]) | ((unsigned)f2bf(ua.w * dsh[c0 + 3]) << 16);
    pa.z = (unsigned)f2bf(ub.x * dsh[c0 + 4]) | ((unsigned)f2bf(ub.y * dsh[c0 + 5]) << 16);
    pa.w = (unsigned)f2bf(ub.z * dsh[c0 + 6]) | ((unsigned)f2bf(ub.w * dsh[c0 + 7]) << 16);
    pb.x = (unsigned)f2bf(va.x) | ((unsigned)f2bf(va.y) << 16);
    pb.y = (unsigned)f2bf(va.z) | ((unsigned)f2bf(va.w) << 16);
    pb.z = (unsigned)f2bf(vb.x) | ((unsigned)f2bf(vb.y) << 16);
    pb.w = (unsigned)f2bf(vb.z) | ((unsigned)f2bf(vb.w) << 16);
    *(uint4*)&As[row][seg * 8] = pa;
    *(uint4*)&Bs[row][seg * 8] = pb;
    __syncthreads();
    bf16x8 af = *(const bf16x8*)&As[w * 16 + (lane & 15)][(lane >> 4) * 8];
#pragma unroll
    for (int nf = 0; nf < 4; ++nf) {
      bf16x8 bf = *(const bf16x8*)&Bs[nf * 16 + (lane & 15)][(lane >> 4) * 8];
      acc[nf] = __builtin_amdgcn_mfma_f32_16x16x32_bf16(af, bf, acc[nf], 0, 0, 0);
    }
  }
#pragma unroll
  for (int nf = 0; nf < 4; ++nf)
#pragma unroll
    for (int r = 0; r < 4; ++r) {
      int ri = i0 + w * 16 + (lane >> 4) * 4 + r;
      int cj = j0 + nf * 16 + (lane & 15);
      P[ri * DIM + cj] = f2bf(acc[nf][r]);
    }
}

// ---------------------------------------------------------------------------
// Stage 6: out = P @ x via bf16 MFMA (unchanged).
__global__ __launch_bounds__(512) void k_gemm(const unsigned short* __restrict__ P,
                                              const float* __restrict__ X,
                                              float* __restrict__ out) {
  __shared__ unsigned short As[DIM][40];
  __shared__ unsigned short Bs[64][40];
  const int tid = threadIdx.x;
  const int lane = tid & 63;
  const int w = tid >> 6;
  const int bn = blockIdx.x * 64;
  const int kk = tid >> 4;
  const int nq = tid & 15;

  const unsigned short* prow = P + tid * DIM;
  uint4 a0 = *(const uint4*)(prow + 0);
  uint4 a1 = *(const uint4*)(prow + 8);
  uint4 a2 = *(const uint4*)(prow + 16);
  uint4 a3 = *(const uint4*)(prow + 24);
  float4 bx = *(const float4*)(X + kk * NCOLS + bn + nq * 4);

  f32x4 acc[4][4];
#pragma unroll
  for (int mf = 0; mf < 4; ++mf)
#pragma unroll
    for (int nf = 0; nf < 4; ++nf)
      acc[mf][nf] = (f32x4){0.f, 0.f, 0.f, 0.f};

#pragma unroll 1
  for (int t = 0; t < 16; ++t) {
    __syncthreads();
    *(uint4*)&As[tid][0] = a0;
    *(uint4*)&As[tid][8] = a1;
    *(uint4*)&As[tid][16] = a2;
    *(uint4*)&As[tid][24] = a3;
    Bs[nq * 4 + 0][kk] = f2bf(bx.x);
    Bs[nq * 4 + 1][kk] = f2bf(bx.y);
    Bs[nq * 4 + 2][kk] = f2bf(bx.z);
    Bs[nq * 4 + 3][kk] = f2bf(bx.w);
    if (t < 15) {
      const unsigned short* pn = prow + (t + 1) * 32;
      a0 = *(const uint4*)(pn + 0);
      a1 = *(const uint4*)(pn + 8);
      a2 = *(const uint4*)(pn + 16);
      a3 = *(const uint4*)(pn + 24);
      bx = *(const float4*)(X + ((t + 1) * 32 + kk) * NCOLS + bn + nq * 4);
    }
    __syncthreads();
    bf16x8 af[4], bf[4];
#pragma unroll
    for (int mf = 0; mf < 4; ++mf)
      af[mf] = *(const bf16x8*)&As[w * 64 + mf * 16 + (lane & 15)][(lane >> 4) * 8];
#pragma unroll
    for (int nf = 0; nf < 4; ++nf)
      bf[nf] = *(const bf16x8*)&Bs[nf * 16 + (lane & 15)][(lane >> 4) * 8];
#pragma unroll
    for (int mf = 0; mf < 4; ++mf)
#pragma unroll
      for (int nf = 0; nf < 4; ++nf)
        acc[mf][nf] = __builtin_amdgcn_mfma_f32_16x16x32_bf16(af[mf], bf[nf],
                                                              acc[mf][nf], 0, 0, 0);
  }

#pragma unroll
  for (int mf = 0; mf < 4; ++mf)
#pragma unroll
    for (int nf = 0; nf < 4; ++nf)
#pragma unroll
      for (int r = 0; r < 4; ++r) {
        int row = w * 64 + mf * 16 + (lane >> 4) * 4 + r;
        int col = bn + nf * 16 + (lane & 15);
        out[row * NCOLS + col] = acc[mf][nf][r];
      }
}

// ---------------------------------------------------------------------------
extern "C" void kernel_launch(void* const* d_in, const int* in_sizes, int n_in,
                              void* d_out, int out_size, void* d_ws, size_t ws_size,
                              hipStream_t stream) {
  const float* X = (const float*)d_in[0];
  const float* W = (const float*)d_in[1];
  const float* Dp = (const float*)d_in[2];
  float* out = (float*)d_out;

  char* ws = (char*)d_ws;
  double* G = (double*)ws;                          // 2 MB: Gram -> L (f64)
  float* Lf = (float*)(ws + (2u << 20));            // 1 MB: L (f32, row-major)
  float* Minv = (float*)(ws + (3u << 20));          // 1 MB: L^-1 (f32)
  float* U = (float*)(ws + (4u << 20));             // 1 MB
  unsigned short* P = (unsigned short*)(ws + (5u << 20));  // 0.5 MB bf16
  float* T = (float*)ws;  // comb temp ALIASES G (G dead before comb runs)

  k_gram<<<dim3(16, 16), 256, 0, stream>>>(W, G);
  hipMemsetAsync(Minv, 0, DIM * DIM * sizeof(float), stream);
  for (int k = 0; k < 16; ++k) {
    k_diag<<<1, 64, 0, stream>>>(G, Lf, k);
    int remRows = DIM - (k + 1) * PB;
    if (remRows > 0) {
      k_trsm<<<(remRows + 63) / 64, 64, 0, stream>>>(G, Lf, k);
      k_syrk<<<dim3(remRows / 32, remRows / 32), 256, 0, stream>>>(G, k);
    }
  }
  k_dinv<<<8, 64, 0, stream>>>(Lf, Minv);
  for (int l = 0; l < 3; ++l) {
    int n = 64 << l, Pn = 4 >> l;
    k_combT<<<dim3(n / 16, n / 16, Pn), 256, 0, stream>>>(Lf, Minv, T, n);
    k_combO<<<dim3(n / 16, n / 16, Pn), 256, 0, stream>>>(Minv, T, n);
  }
  k_formU<<<dim3(16, 16), 256, 0, stream>>>(W, Minv, U);
  k_formP<<<dim3(8, 8), 256, 0, stream>>>(U, Dp, P);
  k_gemm<<<NCOLS / 64, 512, 0, stream>>>(P, X, out);
}